// Round 1
// baseline (227.717 us; speedup 1.0000x reference)
//
#include <hip/hip_runtime.h>
#include <hip/hip_bf16.h>

typedef __hip_bfloat16 bf16;
typedef __attribute__((ext_vector_type(4))) float f32x4;
typedef __attribute__((ext_vector_type(8))) short s16x8;

#define TSEQ 2048
#define NB 4
#define HS 128
#define DM 1024

__device__ __forceinline__ ushort f2bf(float f) {
  bf16 h = __float2bfloat16(f);
  return *reinterpret_cast<ushort*>(&h);
}

// ---------------- fp32 -> bf16 conversion, 4 elems/thread ----------------
__global__ __launch_bounds__(256) void cvt4(const float* __restrict__ src,
                                            ushort* __restrict__ dst, int n4) {
  int i = blockIdx.x * 256 + threadIdx.x;
  if (i >= n4) return;
  const float4 v = reinterpret_cast<const float4*>(src)[i];
  ushort4 o;
  o.x = f2bf(v.x); o.y = f2bf(v.y); o.z = f2bf(v.z); o.w = f2bf(v.w);
  reinterpret_cast<ushort4*>(dst)[i] = o;
}

// ---------------- fused QKV projection GEMM ----------------
// A[8192][1024] bf16 row-major, Bw[384][1024] bf16 (rows = output cols, B^T form).
// Tile 128x128, BK=64, 4 waves (2x2 of 64x64), 16x16x32 MFMA.
// nt (blockIdx.y): 0 -> Q (bias+scale), 1 -> K (bias), 2 -> V^T (bias, [B][H][T]).
__global__ __launch_bounds__(256) void qkv_gemm(
    const ushort* __restrict__ A, const ushort* __restrict__ Bw,
    const float* __restrict__ bq, const float* __restrict__ bk,
    const float* __restrict__ bv,
    ushort* __restrict__ Qb, ushort* __restrict__ Kb, ushort* __restrict__ Vt) {
  __shared__ __align__(16) ushort sA[128 * 64];
  __shared__ __align__(16) ushort sB[128 * 64];
  const int tid = threadIdx.x;
  const int lane = tid & 63;
  const int wv = tid >> 6;
  const int cl = lane & 15;
  const int g4 = lane >> 4;
  const int m0 = blockIdx.x * 128;
  const int nt = blockIdx.y;
  const int n0 = nt * 128;
  const int wr = (wv >> 1) * 64, wc = (wv & 1) * 64;

  f32x4 acc[4][4] = {};

  for (int k0 = 0; k0 < DM; k0 += 64) {
    // stage A,B tiles; LDS granule (row,g) stored at g^(row&7) (rows are 128B)
    for (int i = 0; i < 4; ++i) {
      int c = tid + i * 256;
      int row = c >> 3, g = c & 7;
      s16x8 va = *reinterpret_cast<const s16x8*>(A + (size_t)(m0 + row) * DM + k0 + g * 8);
      *reinterpret_cast<s16x8*>((char*)sA + row * 128 + ((g ^ (row & 7)) << 4)) = va;
      s16x8 vb = *reinterpret_cast<const s16x8*>(Bw + (size_t)(n0 + row) * DM + k0 + g * 8);
      *reinterpret_cast<s16x8*>((char*)sB + row * 128 + ((g ^ (row & 7)) << 4)) = vb;
    }
    __syncthreads();
    for (int kk = 0; kk < 2; ++kk) {
      s16x8 af[4], bfg[4];
      for (int m4 = 0; m4 < 4; ++m4) {
        int row = wr + m4 * 16 + cl;
        int g = kk * 4 + g4;
        af[m4] = *reinterpret_cast<const s16x8*>((const char*)sA + row * 128 + ((g ^ (row & 7)) << 4));
      }
      for (int n4 = 0; n4 < 4; ++n4) {
        int row = wc + n4 * 16 + cl;
        int g = kk * 4 + g4;
        bfg[n4] = *reinterpret_cast<const s16x8*>((const char*)sB + row * 128 + ((g ^ (row & 7)) << 4));
      }
      for (int m4 = 0; m4 < 4; ++m4)
        for (int n4 = 0; n4 < 4; ++n4)
          acc[m4][n4] = __builtin_amdgcn_mfma_f32_16x16x32_bf16(af[m4], bfg[n4], acc[m4][n4], 0, 0, 0);
    }
    __syncthreads();
  }

  const float scale = 0.08838834764831845f;  // 128^-0.5 folded into Q
  for (int m4 = 0; m4 < 4; ++m4)
    for (int n4 = 0; n4 < 4; ++n4) {
      int n_loc = wc + n4 * 16 + cl;  // 0..127
      for (int r = 0; r < 4; ++r) {
        int m = m0 + wr + m4 * 16 + g4 * 4 + r;
        float v = acc[m4][n4][r];
        if (nt == 0) {
          v = (v + bq[n_loc]) * scale;
          Qb[(size_t)m * HS + n_loc] = f2bf(v);
        } else if (nt == 1) {
          v = v + bk[n_loc];
          Kb[(size_t)m * HS + n_loc] = f2bf(v);
        } else {
          v = v + bv[n_loc];
          int bb = m >> 11, t = m & 2047;
          Vt[((size_t)bb * HS + n_loc) * TSEQ + t] = f2bf(v);
        }
      }
    }
}

// ---------------- flash attention ----------------
// grid 256: block = 32 q-rows of one batch; 4 waves kv-split (512 keys each),
// private per-wave LDS tiles -> NO barriers in main loop. KVBLK=32.
// K-tile [32][128] and V^T-tile [128][32] time-share one 8KB buffer.
__global__ __launch_bounds__(256) void attn(const ushort* __restrict__ Qg,
                                            const ushort* __restrict__ Kg,
                                            const ushort* __restrict__ Vt,
                                            float* __restrict__ out) {
  __shared__ __align__(16) char smem[4 * 10240 + 1024];
  const int tid = threadIdx.x;
  const int lane = tid & 63;
  const int wv = tid >> 6;
  const int cl = lane & 15;
  const int g4 = lane >> 4;
  const int b = blockIdx.x >> 6;
  const int q0 = (blockIdx.x & 63) << 5;

  char* sKVb = smem + wv * 10240;        // 8KB shared K-tile / V-tile
  char* sPb = smem + wv * 10240 + 8192;  // 2KB P transpose buffer
  float* sml = (float*)(smem + 40960);   // [4][32][2] merge stats
  float* sO = (float*)smem;              // 16KB merge overlay (after loop)

  // Q fragments in registers (Q is pre-scaled by H^-0.5)
  s16x8 qf_[2][4];
  {
    const ushort* qbase = Qg + (size_t)(b * TSEQ + q0) * HS;
    for (int qf = 0; qf < 2; ++qf)
      for (int kk = 0; kk < 4; ++kk)
        qf_[qf][kk] = *reinterpret_cast<const s16x8*>(qbase + (qf * 16 + cl) * HS + kk * 32 + g4 * 8);
  }

  f32x4 o_[2][8] = {};
  float m_[2][4], l_[2][4];
  for (int qf = 0; qf < 2; ++qf)
    for (int r = 0; r < 4; ++r) { m_[qf][r] = -3.0e38f; l_[qf][r] = 0.f; }

  const int kvwave = wv * 512;
  for (int ti = 0; ti < 16; ++ti) {
    const int kv0 = kvwave + ti * 32;
    // stage K tile [32][128]; rows are 256B -> swizzle g^(row&7) over 16 granules
    {
      const ushort* kb = Kg + (size_t)(b * TSEQ + kv0) * HS;
      for (int i = 0; i < 8; ++i) {
        int c = lane + i * 64;
        int row = c >> 4, g = c & 15;
        s16x8 v = *reinterpret_cast<const s16x8*>(kb + row * HS + g * 8);
        *reinterpret_cast<s16x8*>(sKVb + row * 256 + ((g ^ (row & 7)) << 4)) = v;
      }
    }
    // S = Q * K^T  (C: col=kv=lane&15, row=q)
    f32x4 s_[2][2] = {};
    for (int kk = 0; kk < 4; ++kk)
      for (int kvf = 0; kvf < 2; ++kvf) {
        int row = kvf * 16 + cl;
        int g = kk * 4 + g4;
        s16x8 bfg = *reinterpret_cast<const s16x8*>(sKVb + row * 256 + ((g ^ (row & 7)) << 4));
        s_[0][kvf] = __builtin_amdgcn_mfma_f32_16x16x32_bf16(qf_[0][kk], bfg, s_[0][kvf], 0, 0, 0);
        s_[1][kvf] = __builtin_amdgcn_mfma_f32_16x16x32_bf16(qf_[1][kk], bfg, s_[1][kvf], 0, 0, 0);
      }
    // stage V^T tile [128][32] into same buffer (in-order LDS: safe after K reads)
    {
      const ushort* vb = Vt + (size_t)b * HS * TSEQ + kv0;
      for (int i = 0; i < 8; ++i) {
        int c = lane + i * 64;
        int d = c >> 2, g = c & 3;
        s16x8 v = *reinterpret_cast<const s16x8*>(vb + (size_t)d * TSEQ + g * 8);
        *reinterpret_cast<s16x8*>(sKVb + d * 64 + ((g ^ ((d >> 1) & 3)) << 4)) = v;
      }
    }
    // online softmax (16-lane butterfly per q-row)
    float alpha[2][4];
    for (int qf = 0; qf < 2; ++qf)
      for (int r = 0; r < 4; ++r) {
        float mx = fmaxf(s_[qf][0][r], s_[qf][1][r]);
        for (int msk = 1; msk < 16; msk <<= 1) mx = fmaxf(mx, __shfl_xor(mx, msk, 64));
        float mn = fmaxf(m_[qf][r], mx);
        float al = __expf(m_[qf][r] - mn);
        m_[qf][r] = mn;
        float p0 = __expf(s_[qf][0][r] - mn);
        float p1 = __expf(s_[qf][1][r] - mn);
        s_[qf][0][r] = p0; s_[qf][1][r] = p1;
        float rs = p0 + p1;
        for (int msk = 1; msk < 16; msk <<= 1) rs += __shfl_xor(rs, msk, 64);
        l_[qf][r] = l_[qf][r] * al + rs;
        alpha[qf][r] = al;
      }
    for (int qf = 0; qf < 2; ++qf)
      for (int df = 0; df < 8; ++df)
        for (int r = 0; r < 4; ++r) o_[qf][df][r] *= alpha[qf][r];
    // P -> LDS (transpose to A-fragment layout), rows are 64B -> swz g^((q>>1)&3)
    for (int qf = 0; qf < 2; ++qf)
      for (int kvf = 0; kvf < 2; ++kvf)
        for (int r = 0; r < 4; ++r) {
          int q = qf * 16 + g4 * 4 + r;
          int kv = kvf * 16 + cl;
          *reinterpret_cast<ushort*>(sPb + q * 64 + (((kv >> 3) ^ ((q >> 1) & 3)) << 4) + (kv & 7) * 2) =
              f2bf(s_[qf][kvf][r]);
        }
    // O += P * V
    s16x8 af[2];
    for (int qf = 0; qf < 2; ++qf) {
      int q = qf * 16 + cl;
      af[qf] = *reinterpret_cast<const s16x8*>(sPb + q * 64 + ((g4 ^ ((q >> 1) & 3)) << 4));
    }
    for (int df = 0; df < 8; ++df) {
      int d = df * 16 + cl;
      s16x8 vf = *reinterpret_cast<const s16x8*>(sKVb + d * 64 + ((g4 ^ ((d >> 1) & 3)) << 4));
      o_[0][df] = __builtin_amdgcn_mfma_f32_16x16x32_bf16(af[0], vf, o_[0][df], 0, 0, 0);
      o_[1][df] = __builtin_amdgcn_mfma_f32_16x16x32_bf16(af[1], vf, o_[1][df], 0, 0, 0);
    }
  }

  // ---- merge the 4 kv-split partials ----
  if (cl == 0)
    for (int qf = 0; qf < 2; ++qf)
      for (int r = 0; r < 4; ++r) {
        int row = qf * 16 + g4 * 4 + r;
        sml[(wv * 32 + row) * 2 + 0] = m_[qf][r];
        sml[(wv * 32 + row) * 2 + 1] = l_[qf][r];
      }
  __syncthreads();
  float fac[2][4];
  for (int qf = 0; qf < 2; ++qf)
    for (int r = 0; r < 4; ++r) {
      int row = qf * 16 + g4 * 4 + r;
      float M = -3.0e38f;
      for (int w = 0; w < 4; ++w) M = fmaxf(M, sml[(w * 32 + row) * 2]);
      float L = 0.f;
      for (int w = 0; w < 4; ++w) L += sml[(w * 32 + row) * 2 + 1] * __expf(sml[(w * 32 + row) * 2] - M);
      fac[qf][r] = __expf(m_[qf][r] - M) / L;
    }
  for (int w = 0; w < 4; ++w) {
    if (wv == w) {
      for (int qf = 0; qf < 2; ++qf)
        for (int df = 0; df < 8; ++df)
          for (int r = 0; r < 4; ++r) {
            int q = qf * 16 + g4 * 4 + r;
            int d = df * 16 + cl;
            float val = o_[qf][df][r] * fac[qf][r];
            if (w == 0) sO[q * HS + d] = val;
            else        sO[q * HS + d] += val;
          }
    }
    __syncthreads();
  }
  float* op = out + (size_t)(b * TSEQ + q0) * HS;
  for (int i = tid; i < 32 * HS; i += 256) op[i] = sO[i];
}

extern "C" void kernel_launch(void* const* d_in, const int* in_sizes, int n_in,
                              void* d_out, int out_size, void* d_ws, size_t ws_size,
                              hipStream_t stream) {
  const float* x = (const float*)d_in[0];
  const float* Wq = (const float*)d_in[1];
  const float* bq = (const float*)d_in[2];
  const float* Wk = (const float*)d_in[3];
  const float* bk = (const float*)d_in[4];
  const float* Wv = (const float*)d_in[5];
  const float* bv = (const float*)d_in[6];
  float* out = (float*)d_out;

  char* ws = (char*)d_ws;
  ushort* xb = (ushort*)ws;                    // 8192*1024 bf16 = 16 MB
  ushort* wc = (ushort*)(ws + 16777216);       // 384*1024 bf16
  ushort* Qb = (ushort*)(ws + 17563648);       // 8192*128 bf16 (pre-scaled)
  ushort* Kb = (ushort*)(ws + 19660800);       // 8192*128 bf16
  ushort* Vt = (ushort*)(ws + 21757952);       // 4*128*2048 bf16 (transposed V)

  cvt4<<<8192, 256, 0, stream>>>(x, xb, 2097152);
  cvt4<<<128, 256, 0, stream>>>(Wq, wc, 32768);
  cvt4<<<128, 256, 0, stream>>>(Wk, wc + 131072, 32768);
  cvt4<<<128, 256, 0, stream>>>(Wv, wc + 262144, 32768);
  qkv_gemm<<<dim3(64, 3), 256, 0, stream>>>(xb, wc, bq, bk, bv, Qb, Kb, Vt);
  attn<<<256, 256, 0, stream>>>(Qb, Kb, Vt, out);
}

// Round 12
// 215.800 us; speedup vs baseline: 1.0552x; 1.0552x over previous
//
#include <hip/hip_runtime.h>
#include <hip/hip_bf16.h>

typedef __hip_bfloat16 bf16;
typedef __attribute__((ext_vector_type(4))) float f32x4;
typedef __attribute__((ext_vector_type(8))) short s16x8;

#define TSEQ 2048
#define NB 4
#define HS 128
#define DM 1024

__device__ __forceinline__ ushort f2bf(float f) {
  bf16 h = __float2bfloat16(f);
  return *reinterpret_cast<ushort*>(&h);
}

// ---------------- fp32 -> bf16 conversion, 4 elems/thread ----------------
__global__ __launch_bounds__(256) void cvt4(const float* __restrict__ src,
                                            ushort* __restrict__ dst, int n4) {
  int i = blockIdx.x * 256 + threadIdx.x;
  if (i >= n4) return;
  const float4 v = reinterpret_cast<const float4*>(src)[i];
  ushort4 o;
  o.x = f2bf(v.x); o.y = f2bf(v.y); o.z = f2bf(v.z); o.w = f2bf(v.w);
  reinterpret_cast<ushort4*>(dst)[i] = o;
}

// fused W conversion: 3 segments of 32768 float4s each
__global__ __launch_bounds__(256) void cvtW(const float* __restrict__ Wq,
                                            const float* __restrict__ Wk,
                                            const float* __restrict__ Wv,
                                            ushort* __restrict__ dst) {
  int bid = blockIdx.x;
  int seg = bid >> 7;
  int i = (bid & 127) * 256 + threadIdx.x;
  const float* src = seg == 0 ? Wq : (seg == 1 ? Wk : Wv);
  const float4 v = reinterpret_cast<const float4*>(src)[i];
  ushort4 o;
  o.x = f2bf(v.x); o.y = f2bf(v.y); o.z = f2bf(v.z); o.w = f2bf(v.w);
  reinterpret_cast<ushort4*>(dst + (size_t)seg * 131072)[i] = o;
}

// ---------------- fused QKV projection GEMM ----------------
// A[8192][1024] bf16 row-major, Bw[384][1024] bf16 (rows = output cols, B^T form).
// Tile 64x128, BK=64, 4 waves (2x2 of 32x64), 16x16x32 MFMA. grid (128,3).
// nt: 0 -> Q (bias+scale), 1 -> K (bias), 2 -> V^T (bias, [B][H][T], LDS-transposed store).
__global__ __launch_bounds__(256) void qkv_gemm(
    const ushort* __restrict__ A, const ushort* __restrict__ Bw,
    const float* __restrict__ bq, const float* __restrict__ bk,
    const float* __restrict__ bv,
    ushort* __restrict__ Qb, ushort* __restrict__ Kb, ushort* __restrict__ Vt) {
  __shared__ __align__(16) ushort smem[12288];  // sA 4096 + sB 8192 (24KB); sT overlay 128*68
  ushort* sA = smem;
  ushort* sB = smem + 4096;
  const int tid = threadIdx.x;
  const int lane = tid & 63;
  const int wv = tid >> 6;
  const int cl = lane & 15;
  const int g4 = lane >> 4;
  const int m0 = blockIdx.x * 64;
  const int nt = blockIdx.y;
  const int n0 = nt * 128;
  const int wr = (wv >> 1) * 32, wc = (wv & 1) * 64;

  f32x4 acc[2][4] = {};

  for (int k0 = 0; k0 < DM; k0 += 64) {
    for (int i = 0; i < 2; ++i) {  // A: 64 rows x 8 granules
      int c = tid + i * 256;
      int row = c >> 3, g = c & 7;
      s16x8 va = *reinterpret_cast<const s16x8*>(A + (size_t)(m0 + row) * DM + k0 + g * 8);
      *reinterpret_cast<s16x8*>((char*)sA + row * 128 + ((g ^ (row & 7)) << 4)) = va;
    }
    for (int i = 0; i < 4; ++i) {  // B: 128 rows x 8 granules
      int c = tid + i * 256;
      int row = c >> 3, g = c & 7;
      s16x8 vb = *reinterpret_cast<const s16x8*>(Bw + (size_t)(n0 + row) * DM + k0 + g * 8);
      *reinterpret_cast<s16x8*>((char*)sB + row * 128 + ((g ^ (row & 7)) << 4)) = vb;
    }
    __syncthreads();
    for (int kk = 0; kk < 2; ++kk) {
      s16x8 af[2], bfg[4];
      for (int m4 = 0; m4 < 2; ++m4) {
        int row = wr + m4 * 16 + cl;
        int g = kk * 4 + g4;
        af[m4] = *reinterpret_cast<const s16x8*>((const char*)sA + row * 128 + ((g ^ (row & 7)) << 4));
      }
      for (int n4 = 0; n4 < 4; ++n4) {
        int row = wc + n4 * 16 + cl;
        int g = kk * 4 + g4;
        bfg[n4] = *reinterpret_cast<const s16x8*>((const char*)sB + row * 128 + ((g ^ (row & 7)) << 4));
      }
      for (int m4 = 0; m4 < 2; ++m4)
        for (int n4 = 0; n4 < 4; ++n4)
          acc[m4][n4] = __builtin_amdgcn_mfma_f32_16x16x32_bf16(af[m4], bfg[n4], acc[m4][n4], 0, 0, 0);
    }
    __syncthreads();
  }

  const float scale = 0.08838834764831845f;  // 128^-0.5 folded into Q
  if (nt < 2) {
    for (int m4 = 0; m4 < 2; ++m4)
      for (int n4 = 0; n4 < 4; ++n4) {
        int n_loc = wc + n4 * 16 + cl;
        for (int r = 0; r < 4; ++r) {
          int m = m0 + wr + m4 * 16 + g4 * 4 + r;
          float v = acc[m4][n4][r];
          if (nt == 0) {
            v = (v + bq[n_loc]) * scale;
            Qb[(size_t)m * HS + n_loc] = f2bf(v);
          } else {
            v = v + bk[n_loc];
            Kb[(size_t)m * HS + n_loc] = f2bf(v);
          }
        }
      }
  } else {
    // V^T: transpose through LDS, store coalesced rows of Vt[B][H][T]
    ushort* sT = smem;  // [128 n][68] (pad 4)
    for (int m4 = 0; m4 < 2; ++m4)
      for (int n4 = 0; n4 < 4; ++n4) {
        int n_loc = wc + n4 * 16 + cl;
        for (int r = 0; r < 4; ++r) {
          int ml = wr + m4 * 16 + g4 * 4 + r;
          sT[n_loc * 68 + ml] = f2bf(acc[m4][n4][r] + bv[n_loc]);
        }
      }
    __syncthreads();
    const int bb = m0 >> 11;
    const int t0 = m0 & 2047;
    int n = tid >> 1, mh = (tid & 1) * 32;
    ushort* dst = Vt + ((size_t)bb * HS + n) * TSEQ + t0 + mh;
    for (int j = 0; j < 4; ++j) {
      s16x8 v = *reinterpret_cast<const s16x8*>(sT + n * 68 + mh + j * 8);
      *reinterpret_cast<s16x8*>(dst + j * 8) = v;
    }
  }
}

// ---------------- flash attention ----------------
// grid 512 (XCD-chunk-swizzled): block = 16 q-rows of one batch; 8 waves kv-split
// (256 keys each, 8 iters of KVBLK=32), private per-wave LDS tiles -> NO barriers
// in main loop. K-tile [32][128] and V^T-tile [128][32] time-share one 8KB buffer.
#define WLDS 9216
__global__ __launch_bounds__(512, 4) void attn(const ushort* __restrict__ Qg,
                                               const ushort* __restrict__ Kg,
                                               const ushort* __restrict__ Vt,
                                               float* __restrict__ out) {
  __shared__ __align__(16) char smem[8 * WLDS + 1024];
  const int tid = threadIdx.x;
  const int lane = tid & 63;
  const int wv = tid >> 6;
  const int cl = lane & 15;
  const int g4 = lane >> 4;
  const int bid = blockIdx.x;
  const int swz = (bid & 7) * 64 + (bid >> 3);  // XCD-chunked (512 % 8 == 0)
  const int b = swz >> 7;
  const int q0 = (swz & 127) << 4;

  char* sKVb = smem + wv * WLDS;        // 8KB shared K-tile / V-tile
  char* sPb = smem + wv * WLDS + 8192;  // 1KB P transpose buffer
  float* sml = (float*)(smem + 8 * WLDS);  // [8][16][2] merge stats
  float* sO = (float*)smem;                // 8KB merge overlay (after loop)

  // Q fragment in registers (Q pre-scaled by H^-0.5): A-frag row=cl, k granule g4
  s16x8 qf_[4];
  {
    const ushort* qbase = Qg + (size_t)(b * TSEQ + q0 + cl) * HS;
    for (int kk = 0; kk < 4; ++kk)
      qf_[kk] = *reinterpret_cast<const s16x8*>(qbase + kk * 32 + g4 * 8);
  }

  f32x4 o_[8] = {};
  float m_[4], l_[4];
  for (int r = 0; r < 4; ++r) { m_[r] = -3.0e38f; l_[r] = 0.f; }

  const int kvwave = wv * 256;
  for (int ti = 0; ti < 8; ++ti) {
    const int kv0 = kvwave + ti * 32;
    // stage K tile [32][128]; rows 256B -> swizzle g^(row&7) over 16 granules
    {
      const ushort* kb = Kg + (size_t)(b * TSEQ + kv0) * HS;
      for (int i = 0; i < 8; ++i) {
        int c = lane + i * 64;
        int row = c >> 4, g = c & 15;
        s16x8 v = *reinterpret_cast<const s16x8*>(kb + row * HS + g * 8);
        *reinterpret_cast<s16x8*>(sKVb + row * 256 + ((g ^ (row & 7)) << 4)) = v;
      }
    }
    // S = Q * K^T : C row=q=g4*4+r, col=kv=cl (per kvf frag)
    f32x4 s_[2] = {};
    for (int kk = 0; kk < 4; ++kk)
      for (int kvf = 0; kvf < 2; ++kvf) {
        int row = kvf * 16 + cl;
        int g = kk * 4 + g4;
        s16x8 bfg = *reinterpret_cast<const s16x8*>(sKVb + row * 256 + ((g ^ (row & 7)) << 4));
        s_[kvf] = __builtin_amdgcn_mfma_f32_16x16x32_bf16(qf_[kk], bfg, s_[kvf], 0, 0, 0);
      }
    // stage V^T tile [128][32] into same buffer (same-wave DS in-order: safe after K reads)
    {
      const ushort* vb = Vt + (size_t)b * HS * TSEQ + kv0;
      for (int i = 0; i < 8; ++i) {
        int c = lane + i * 64;
        int d = c >> 2, g = c & 3;
        s16x8 v = *reinterpret_cast<const s16x8*>(vb + (size_t)d * TSEQ + g * 8);
        *reinterpret_cast<s16x8*>(sKVb + d * 64 + ((g ^ ((d >> 1) & 3)) << 4)) = v;
      }
    }
    // online softmax (16-lane butterfly per q-row; rows r=0..3 per lane-group)
    for (int r = 0; r < 4; ++r) {
      float mx = fmaxf(s_[0][r], s_[1][r]);
      for (int msk = 1; msk < 16; msk <<= 1) mx = fmaxf(mx, __shfl_xor(mx, msk, 64));
      float mn = fmaxf(m_[r], mx);
      float al = __expf(m_[r] - mn);
      m_[r] = mn;
      float p0 = __expf(s_[0][r] - mn);
      float p1 = __expf(s_[1][r] - mn);
      s_[0][r] = p0; s_[1][r] = p1;
      float rs = p0 + p1;
      for (int msk = 1; msk < 16; msk <<= 1) rs += __shfl_xor(rs, msk, 64);
      l_[r] = l_[r] * al + rs;
      for (int df = 0; df < 8; ++df) o_[df][r] *= al;
    }
    // P -> LDS (transpose to A-fragment layout), rows 64B -> swz (kv>>3)^((q>>1)&3)
    for (int kvf = 0; kvf < 2; ++kvf)
      for (int r = 0; r < 4; ++r) {
        int q = g4 * 4 + r;
        int kv = kvf * 16 + cl;
        *reinterpret_cast<ushort*>(sPb + q * 64 + (((kv >> 3) ^ ((q >> 1) & 3)) << 4) + (kv & 7) * 2) =
            f2bf(s_[kvf][r]);
      }
    // O += P * V
    s16x8 af = *reinterpret_cast<const s16x8*>(sPb + cl * 64 + ((g4 ^ ((cl >> 1) & 3)) << 4));
    for (int df = 0; df < 8; ++df) {
      int d = df * 16 + cl;
      s16x8 vf = *reinterpret_cast<const s16x8*>(sKVb + d * 64 + ((g4 ^ ((d >> 1) & 3)) << 4));
      o_[df] = __builtin_amdgcn_mfma_f32_16x16x32_bf16(af, vf, o_[df], 0, 0, 0);
    }
  }

  // ---- merge the 8 kv-split partials (LDS atomics, no serialization) ----
  if (cl == 0)
    for (int r = 0; r < 4; ++r) {
      int row = g4 * 4 + r;
      sml[(wv * 16 + row) * 2 + 0] = m_[r];
      sml[(wv * 16 + row) * 2 + 1] = l_[r];
    }
  __syncthreads();
  float fac[4];
  for (int r = 0; r < 4; ++r) {
    int row = g4 * 4 + r;
    float M = -3.0e38f;
    for (int w = 0; w < 8; ++w) M = fmaxf(M, sml[(w * 16 + row) * 2]);
    float L = 0.f;
    for (int w = 0; w < 8; ++w) L += sml[(w * 16 + row) * 2 + 1] * __expf(sml[(w * 16 + row) * 2] - M);
    fac[r] = __expf(m_[r] - M) / L;
  }
  __syncthreads();  // sml read done; sO overlays smem start
  for (int i = tid; i < 16 * HS; i += 512) sO[i] = 0.f;
  __syncthreads();
  for (int df = 0; df < 8; ++df)
    for (int r = 0; r < 4; ++r) {
      int q = g4 * 4 + r;
      int d = df * 16 + cl;
      atomicAdd(&sO[q * HS + d], o_[df][r] * fac[r]);
    }
  __syncthreads();
  float* op = out + (size_t)(b * TSEQ + q0) * HS;
  reinterpret_cast<float4*>(op)[tid] = reinterpret_cast<const float4*>(sO)[tid];
}

extern "C" void kernel_launch(void* const* d_in, const int* in_sizes, int n_in,
                              void* d_out, int out_size, void* d_ws, size_t ws_size,
                              hipStream_t stream) {
  const float* x = (const float*)d_in[0];
  const float* Wq = (const float*)d_in[1];
  const float* bq = (const float*)d_in[2];
  const float* Wk = (const float*)d_in[3];
  const float* bk = (const float*)d_in[4];
  const float* Wv = (const float*)d_in[5];
  const float* bv = (const float*)d_in[6];
  float* out = (float*)d_out;

  char* ws = (char*)d_ws;
  ushort* xb = (ushort*)ws;                    // 8192*1024 bf16 = 16 MB
  ushort* wc = (ushort*)(ws + 16777216);       // 384*1024 bf16
  ushort* Qb = (ushort*)(ws + 17563648);       // 8192*128 bf16 (pre-scaled)
  ushort* Kb = (ushort*)(ws + 19660800);       // 8192*128 bf16
  ushort* Vt = (ushort*)(ws + 21757952);       // 4*128*2048 bf16 (transposed V)

  cvt4<<<8192, 256, 0, stream>>>(x, xb, 2097152);
  cvtW<<<384, 256, 0, stream>>>(Wq, Wk, Wv, wc);
  qkv_gemm<<<dim3(128, 3), 256, 0, stream>>>(xb, wc, bq, bk, bv, Qb, Kb, Vt);
  attn<<<512, 512, 0, stream>>>(Qb, Kb, Vt, out);
}

// Round 13
// 213.042 us; speedup vs baseline: 1.0689x; 1.0129x over previous
//
#include <hip/hip_runtime.h>
#include <hip/hip_bf16.h>

typedef __hip_bfloat16 bf16;
typedef __attribute__((ext_vector_type(4))) float f32x4;
typedef __attribute__((ext_vector_type(8))) short s16x8;

#define TSEQ 2048
#define NB 4
#define HS 128
#define DM 1024

__device__ __forceinline__ ushort f2bf(float f) {
  bf16 h = __float2bfloat16(f);
  return *reinterpret_cast<ushort*>(&h);
}

// ---------------- fp32 -> bf16 conversion, 4 elems/thread ----------------
__global__ __launch_bounds__(256) void cvt4(const float* __restrict__ src,
                                            ushort* __restrict__ dst, int n4) {
  int i = blockIdx.x * 256 + threadIdx.x;
  if (i >= n4) return;
  const float4 v = reinterpret_cast<const float4*>(src)[i];
  ushort4 o;
  o.x = f2bf(v.x); o.y = f2bf(v.y); o.z = f2bf(v.z); o.w = f2bf(v.w);
  reinterpret_cast<ushort4*>(dst)[i] = o;
}

// fused W conversion: 3 segments of 32768 float4s each
__global__ __launch_bounds__(256) void cvtW(const float* __restrict__ Wq,
                                            const float* __restrict__ Wk,
                                            const float* __restrict__ Wv,
                                            ushort* __restrict__ dst) {
  int bid = blockIdx.x;
  int seg = bid >> 7;
  int i = (bid & 127) * 256 + threadIdx.x;
  const float* src = seg == 0 ? Wq : (seg == 1 ? Wk : Wv);
  const float4 v = reinterpret_cast<const float4*>(src)[i];
  ushort4 o;
  o.x = f2bf(v.x); o.y = f2bf(v.y); o.z = f2bf(v.z); o.w = f2bf(v.w);
  reinterpret_cast<ushort4*>(dst + (size_t)seg * 131072)[i] = o;
}

// ---------------- fused QKV projection GEMM (unchanged, measured next) ----
__global__ __launch_bounds__(256) void qkv_gemm(
    const ushort* __restrict__ A, const ushort* __restrict__ Bw,
    const float* __restrict__ bq, const float* __restrict__ bk,
    const float* __restrict__ bv,
    ushort* __restrict__ Qb, ushort* __restrict__ Kb, ushort* __restrict__ Vt) {
  __shared__ __align__(16) ushort smem[12288];
  ushort* sA = smem;
  ushort* sB = smem + 4096;
  const int tid = threadIdx.x;
  const int lane = tid & 63;
  const int wv = tid >> 6;
  const int cl = lane & 15;
  const int g4 = lane >> 4;
  const int m0 = blockIdx.x * 64;
  const int nt = blockIdx.y;
  const int n0 = nt * 128;
  const int wr = (wv >> 1) * 32, wc = (wv & 1) * 64;

  f32x4 acc[2][4] = {};

  for (int k0 = 0; k0 < DM; k0 += 64) {
    for (int i = 0; i < 2; ++i) {
      int c = tid + i * 256;
      int row = c >> 3, g = c & 7;
      s16x8 va = *reinterpret_cast<const s16x8*>(A + (size_t)(m0 + row) * DM + k0 + g * 8);
      *reinterpret_cast<s16x8*>((char*)sA + row * 128 + ((g ^ (row & 7)) << 4)) = va;
    }
    for (int i = 0; i < 4; ++i) {
      int c = tid + i * 256;
      int row = c >> 3, g = c & 7;
      s16x8 vb = *reinterpret_cast<const s16x8*>(Bw + (size_t)(n0 + row) * DM + k0 + g * 8);
      *reinterpret_cast<s16x8*>((char*)sB + row * 128 + ((g ^ (row & 7)) << 4)) = vb;
    }
    __syncthreads();
    for (int kk = 0; kk < 2; ++kk) {
      s16x8 af[2], bfg[4];
      for (int m4 = 0; m4 < 2; ++m4) {
        int row = wr + m4 * 16 + cl;
        int g = kk * 4 + g4;
        af[m4] = *reinterpret_cast<const s16x8*>((const char*)sA + row * 128 + ((g ^ (row & 7)) << 4));
      }
      for (int n4 = 0; n4 < 4; ++n4) {
        int row = wc + n4 * 16 + cl;
        int g = kk * 4 + g4;
        bfg[n4] = *reinterpret_cast<const s16x8*>((const char*)sB + row * 128 + ((g ^ (row & 7)) << 4));
      }
      for (int m4 = 0; m4 < 2; ++m4)
        for (int n4 = 0; n4 < 4; ++n4)
          acc[m4][n4] = __builtin_amdgcn_mfma_f32_16x16x32_bf16(af[m4], bfg[n4], acc[m4][n4], 0, 0, 0);
    }
    __syncthreads();
  }

  const float scale = 0.08838834764831845f;
  if (nt < 2) {
    for (int m4 = 0; m4 < 2; ++m4)
      for (int n4 = 0; n4 < 4; ++n4) {
        int n_loc = wc + n4 * 16 + cl;
        for (int r = 0; r < 4; ++r) {
          int m = m0 + wr + m4 * 16 + g4 * 4 + r;
          float v = acc[m4][n4][r];
          if (nt == 0) {
            v = (v + bq[n_loc]) * scale;
            Qb[(size_t)m * HS + n_loc] = f2bf(v);
          } else {
            v = v + bk[n_loc];
            Kb[(size_t)m * HS + n_loc] = f2bf(v);
          }
        }
      }
  } else {
    ushort* sT = smem;  // [128 n][68]
    for (int m4 = 0; m4 < 2; ++m4)
      for (int n4 = 0; n4 < 4; ++n4) {
        int n_loc = wc + n4 * 16 + cl;
        for (int r = 0; r < 4; ++r) {
          int ml = wr + m4 * 16 + g4 * 4 + r;
          sT[n_loc * 68 + ml] = f2bf(acc[m4][n4][r] + bv[n_loc]);
        }
      }
    __syncthreads();
    const int bb = m0 >> 11;
    const int t0 = m0 & 2047;
    int n = tid >> 1, mh = (tid & 1) * 32;
    ushort* dst = Vt + ((size_t)bb * HS + n) * TSEQ + t0 + mh;
    for (int j = 0; j < 4; ++j) {
      s16x8 v = *reinterpret_cast<const s16x8*>(sT + n * 68 + mh + j * 8);
      *reinterpret_cast<s16x8*>(dst + j * 8) = v;
    }
  }
}

// ---------------- flash attention, v2: swapped-operand QK^T ----------------
// grid 512 (XCD-chunk-swizzled), 8 waves kv-split as before. Changes vs v1:
//  * mfma(K,Q): S[kv=g4*4+r][q=cl] -> softmax is in-lane (8 regs) + 2 shfl_xor
//    (msk 16,32 across g4 groups); m,l are per-lane scalars.
//  * K and V^T fragments loaded DIRECTLY from global (L2-resident, 1MB/batch);
//    no K/V LDS staging at all.
//  * PV = mfma(V^T, P): O[d=df*16+g4*4+r][q=cl]; P via 1KB/wave LDS transpose
//    (2x ds_write_b64 + 1x ds_read_b128, XOR-swizzled by (cl&3)<<4).
__global__ __launch_bounds__(512, 2) void attn(const ushort* __restrict__ Qg,
                                               const ushort* __restrict__ Kg,
                                               const ushort* __restrict__ Vt,
                                               float* __restrict__ out) {
  __shared__ __align__(16) char smem[8 * 1024 + 1024];  // 8x1KB P | 1KB sml; sO overlays P
  const int tid = threadIdx.x;
  const int lane = tid & 63;
  const int wv = tid >> 6;
  const int cl = lane & 15;
  const int g4 = lane >> 4;
  const int bid = blockIdx.x;
  const int swz = (bid & 7) * 64 + (bid >> 3);  // XCD-chunked (512 % 8 == 0)
  const int b = swz >> 7;
  const int q0 = (swz & 127) << 4;

  char* sPb = smem + wv * 1024;            // [16 q][32 kv] bf16, swizzled
  float* sml = (float*)(smem + 8192);      // [8][16][2]
  float* sO = (float*)smem;                // merge overlay (after loop)

  // Q B-frag (pre-scaled): lane holds Q[q0+cl][kk*32 + g4*8 ..+7]
  s16x8 qf_[4];
  {
    const ushort* qbase = Qg + (size_t)(b * TSEQ + q0 + cl) * HS;
    for (int kk = 0; kk < 4; ++kk)
      qf_[kk] = *reinterpret_cast<const s16x8*>(qbase + kk * 32 + g4 * 8);
  }

  const ushort* kbase = Kg + (size_t)b * TSEQ * HS;
  const ushort* vbase = Vt + (size_t)b * HS * TSEQ;
  const int pswz = (cl & 3) << 4;

  f32x4 o_[8] = {};                 // O[d=df*16+g4*4+r][q=cl]
  float m_ = -3.0e38f, l_ = 0.f;    // per-lane (q=cl) running stats

  const int kvwave = wv * 256;
  for (int ti = 0; ti < 8; ++ti) {
    const int kv0 = kvwave + ti * 32;
    // K A-frags direct from global: K[kv0+kvf*16+cl][kk*32+g4*8 ..+7]
    s16x8 kf[2][4];
    for (int kvf = 0; kvf < 2; ++kvf)
      for (int kk = 0; kk < 4; ++kk)
        kf[kvf][kk] = *reinterpret_cast<const s16x8*>(
            kbase + (size_t)(kv0 + kvf * 16 + cl) * HS + kk * 32 + g4 * 8);
    // V A-frags direct from global: V^T[df*16+cl][kv0+g4*8 ..+7]
    s16x8 vf[8];
    for (int df = 0; df < 8; ++df)
      vf[df] = *reinterpret_cast<const s16x8*>(
          vbase + (size_t)(df * 16 + cl) * TSEQ + kv0 + g4 * 8);

    // S = K·Q^T (swapped): S[kv=kvf*16+g4*4+r][q=cl]
    f32x4 s_[2] = {};
    for (int kk = 0; kk < 4; ++kk) {
      s_[0] = __builtin_amdgcn_mfma_f32_16x16x32_bf16(kf[0][kk], qf_[kk], s_[0], 0, 0, 0);
      s_[1] = __builtin_amdgcn_mfma_f32_16x16x32_bf16(kf[1][kk], qf_[kk], s_[1], 0, 0, 0);
    }

    // online softmax: in-lane max/sum over 8 values + cross-g4 butterfly
    float mx = s_[0][0];
    for (int r = 1; r < 4; ++r) mx = fmaxf(mx, s_[0][r]);
    for (int r = 0; r < 4; ++r) mx = fmaxf(mx, s_[1][r]);
    mx = fmaxf(mx, __shfl_xor(mx, 16, 64));
    mx = fmaxf(mx, __shfl_xor(mx, 32, 64));
    float mn = fmaxf(m_, mx);
    float al = __expf(m_ - mn);
    m_ = mn;
    float p0[4], p1[4], rs = 0.f;
    for (int r = 0; r < 4; ++r) { p0[r] = __expf(s_[0][r] - mn); rs += p0[r]; }
    for (int r = 0; r < 4; ++r) { p1[r] = __expf(s_[1][r] - mn); rs += p1[r]; }
    rs += __shfl_xor(rs, 16, 64);
    rs += __shfl_xor(rs, 32, 64);
    l_ = l_ * al + rs;
    for (int df = 0; df < 8; ++df)
      for (int r = 0; r < 4; ++r) o_[df][r] *= al;

    // P -> LDS transpose: value P[kv=kvf*16+g4*4+r][q=cl] at byte kv*2 of row cl
    {
      ushort4 w0, w1;
      w0.x = f2bf(p0[0]); w0.y = f2bf(p0[1]); w0.z = f2bf(p0[2]); w0.w = f2bf(p0[3]);
      w1.x = f2bf(p1[0]); w1.y = f2bf(p1[1]); w1.z = f2bf(p1[2]); w1.w = f2bf(p1[3]);
      *reinterpret_cast<ushort4*>(sPb + ((cl * 64 + 0 * 32 + g4 * 8) ^ pswz)) = w0;
      *reinterpret_cast<ushort4*>(sPb + ((cl * 64 + 1 * 32 + g4 * 8) ^ pswz)) = w1;
    }
    // B-frag read: P[q=cl][kv=g4*8 ..+7] (same-wave LDS ordering guarantees visibility)
    s16x8 paf = *reinterpret_cast<const s16x8*>(sPb + ((cl * 64 + g4 * 16) ^ pswz));

    // O += V^T · P : C[d=g4*4+r (block df)][q=cl]
    for (int df = 0; df < 8; ++df)
      o_[df] = __builtin_amdgcn_mfma_f32_16x16x32_bf16(vf[df], paf, o_[df], 0, 0, 0);
  }

  // ---- merge the 8 kv-split partials (per-lane stats, LDS atomics) ----
  if (g4 == 0) {
    sml[(wv * 16 + cl) * 2 + 0] = m_;
    sml[(wv * 16 + cl) * 2 + 1] = l_;
  }
  __syncthreads();
  float M = -3.0e38f;
  for (int w = 0; w < 8; ++w) M = fmaxf(M, sml[(w * 16 + cl) * 2]);
  float L = 0.f;
  for (int w = 0; w < 8; ++w) L += sml[(w * 16 + cl) * 2 + 1] * __expf(sml[(w * 16 + cl) * 2] - M);
  const float fac = __expf(m_ - M) / L;
  __syncthreads();  // sml read done; sO overlays P region
  for (int i = tid; i < 16 * HS; i += 512) sO[i] = 0.f;
  __syncthreads();
  for (int df = 0; df < 8; ++df)
    for (int r = 0; r < 4; ++r)
      atomicAdd(&sO[cl * HS + df * 16 + g4 * 4 + r], o_[df][r] * fac);
  __syncthreads();
  float* op = out + (size_t)(b * TSEQ + q0) * HS;
  reinterpret_cast<float4*>(op)[tid] = reinterpret_cast<const float4*>(sO)[tid];
}

extern "C" void kernel_launch(void* const* d_in, const int* in_sizes, int n_in,
                              void* d_out, int out_size, void* d_ws, size_t ws_size,
                              hipStream_t stream) {
  const float* x = (const float*)d_in[0];
  const float* Wq = (const float*)d_in[1];
  const float* bq = (const float*)d_in[2];
  const float* Wk = (const float*)d_in[3];
  const float* bk = (const float*)d_in[4];
  const float* Wv = (const float*)d_in[5];
  const float* bv = (const float*)d_in[6];
  float* out = (float*)d_out;

  char* ws = (char*)d_ws;
  ushort* xb = (ushort*)ws;                    // 8192*1024 bf16 = 16 MB
  ushort* wc = (ushort*)(ws + 16777216);       // 384*1024 bf16
  ushort* Qb = (ushort*)(ws + 17563648);       // 8192*128 bf16 (pre-scaled)
  ushort* Kb = (ushort*)(ws + 19660800);       // 8192*128 bf16
  ushort* Vt = (ushort*)(ws + 21757952);       // 4*128*2048 bf16 (transposed V)

  cvt4<<<8192, 256, 0, stream>>>(x, xb, 2097152);
  cvtW<<<384, 256, 0, stream>>>(Wq, Wk, Wv, wc);
  qkv_gemm<<<dim3(128, 3), 256, 0, stream>>>(xb, wc, bq, bk, bv, Qb, Kb, Vt);
  attn<<<512, 512, 0, stream>>>(Qb, Kb, Vt, out);
}

// Round 15
// 212.796 us; speedup vs baseline: 1.0701x; 1.0012x over previous
//
#include <hip/hip_runtime.h>
#include <hip/hip_bf16.h>

typedef __hip_bfloat16 bf16;
typedef __attribute__((ext_vector_type(4))) float f32x4;
typedef __attribute__((ext_vector_type(8))) short s16x8;

#define TSEQ 2048
#define NB 4
#define HS 128
#define DM 1024

__device__ __forceinline__ ushort f2bf(float f) {
  bf16 h = __float2bfloat16(f);
  return *reinterpret_cast<ushort*>(&h);
}

// ---------------- fp32 -> bf16 conversion, 4 elems/thread ----------------
__global__ __launch_bounds__(256) void cvt4(const float* __restrict__ src,
                                            ushort* __restrict__ dst, int n4) {
  int i = blockIdx.x * 256 + threadIdx.x;
  if (i >= n4) return;
  const float4 v = reinterpret_cast<const float4*>(src)[i];
  ushort4 o;
  o.x = f2bf(v.x); o.y = f2bf(v.y); o.z = f2bf(v.z); o.w = f2bf(v.w);
  reinterpret_cast<ushort4*>(dst)[i] = o;
}

// fused W conversion: 3 segments of 32768 float4s each
__global__ __launch_bounds__(256) void cvtW(const float* __restrict__ Wq,
                                            const float* __restrict__ Wk,
                                            const float* __restrict__ Wv,
                                            ushort* __restrict__ dst) {
  int bid = blockIdx.x;
  int seg = bid >> 7;
  int i = (bid & 127) * 256 + threadIdx.x;
  const float* src = seg == 0 ? Wq : (seg == 1 ? Wk : Wv);
  const float4 v = reinterpret_cast<const float4*>(src)[i];
  ushort4 o;
  o.x = f2bf(v.x); o.y = f2bf(v.y); o.z = f2bf(v.z); o.w = f2bf(v.w);
  reinterpret_cast<ushort4*>(dst + (size_t)seg * 131072)[i] = o;
}

// ---------------- fused QKV projection GEMM (unchanged) ----
__global__ __launch_bounds__(256) void qkv_gemm(
    const ushort* __restrict__ A, const ushort* __restrict__ Bw,
    const float* __restrict__ bq, const float* __restrict__ bk,
    const float* __restrict__ bv,
    ushort* __restrict__ Qb, ushort* __restrict__ Kb, ushort* __restrict__ Vt) {
  __shared__ __align__(16) ushort smem[12288];
  ushort* sA = smem;
  ushort* sB = smem + 4096;
  const int tid = threadIdx.x;
  const int lane = tid & 63;
  const int wv = tid >> 6;
  const int cl = lane & 15;
  const int g4 = lane >> 4;
  const int m0 = blockIdx.x * 64;
  const int nt = blockIdx.y;
  const int n0 = nt * 128;
  const int wr = (wv >> 1) * 32, wc = (wv & 1) * 64;

  f32x4 acc[2][4] = {};

  for (int k0 = 0; k0 < DM; k0 += 64) {
    for (int i = 0; i < 2; ++i) {
      int c = tid + i * 256;
      int row = c >> 3, g = c & 7;
      s16x8 va = *reinterpret_cast<const s16x8*>(A + (size_t)(m0 + row) * DM + k0 + g * 8);
      *reinterpret_cast<s16x8*>((char*)sA + row * 128 + ((g ^ (row & 7)) << 4)) = va;
    }
    for (int i = 0; i < 4; ++i) {
      int c = tid + i * 256;
      int row = c >> 3, g = c & 7;
      s16x8 vb = *reinterpret_cast<const s16x8*>(Bw + (size_t)(n0 + row) * DM + k0 + g * 8);
      *reinterpret_cast<s16x8*>((char*)sB + row * 128 + ((g ^ (row & 7)) << 4)) = vb;
    }
    __syncthreads();
    for (int kk = 0; kk < 2; ++kk) {
      s16x8 af[2], bfg[4];
      for (int m4 = 0; m4 < 2; ++m4) {
        int row = wr + m4 * 16 + cl;
        int g = kk * 4 + g4;
        af[m4] = *reinterpret_cast<const s16x8*>((const char*)sA + row * 128 + ((g ^ (row & 7)) << 4));
      }
      for (int n4 = 0; n4 < 4; ++n4) {
        int row = wc + n4 * 16 + cl;
        int g = kk * 4 + g4;
        bfg[n4] = *reinterpret_cast<const s16x8*>((const char*)sB + row * 128 + ((g ^ (row & 7)) << 4));
      }
      for (int m4 = 0; m4 < 2; ++m4)
        for (int n4 = 0; n4 < 4; ++n4)
          acc[m4][n4] = __builtin_amdgcn_mfma_f32_16x16x32_bf16(af[m4], bfg[n4], acc[m4][n4], 0, 0, 0);
    }
    __syncthreads();
  }

  const float scale = 0.08838834764831845f;
  if (nt < 2) {
    for (int m4 = 0; m4 < 2; ++m4)
      for (int n4 = 0; n4 < 4; ++n4) {
        int n_loc = wc + n4 * 16 + cl;
        for (int r = 0; r < 4; ++r) {
          int m = m0 + wr + m4 * 16 + g4 * 4 + r;
          float v = acc[m4][n4][r];
          if (nt == 0) {
            v = (v + bq[n_loc]) * scale;
            Qb[(size_t)m * HS + n_loc] = f2bf(v);
          } else {
            v = v + bk[n_loc];
            Kb[(size_t)m * HS + n_loc] = f2bf(v);
          }
        }
      }
  } else {
    ushort* sT = smem;  // [128 n][68]
    for (int m4 = 0; m4 < 2; ++m4)
      for (int n4 = 0; n4 < 4; ++n4) {
        int n_loc = wc + n4 * 16 + cl;
        for (int r = 0; r < 4; ++r) {
          int ml = wr + m4 * 16 + g4 * 4 + r;
          sT[n_loc * 68 + ml] = f2bf(acc[m4][n4][r] + bv[n_loc]);
        }
      }
    __syncthreads();
    const int bb = m0 >> 11;
    const int t0 = m0 & 2047;
    int n = tid >> 1, mh = (tid & 1) * 32;
    ushort* dst = Vt + ((size_t)bb * HS + n) * TSEQ + t0 + mh;
    for (int j = 0; j < 4; ++j) {
      s16x8 v = *reinterpret_cast<const s16x8*>(sT + n * 68 + mh + j * 8);
      *reinterpret_cast<s16x8*>(dst + j * 8) = v;
    }
  }
}

// ---------------- flash attention, v3: 2 independent kv-tiles per iteration ----
// Same swapped-operand layout as v2 (S[kv][q], per-lane softmax stats, direct
// global K/V fragment loads). Change: each loop step processes kv-tiles A and B
// (64 keys) with independent QK^T chains, 32 loads in flight, ONE softmax
// update + ONE O-rescale per 64 keys, and 16 PV MFMAs with 2x ILP.
// Trades occupancy (~180 VGPR -> 1 block/CU) for ILP: R12 proved TLP doesn't
// help; this tests the ILP axis.
__global__ __launch_bounds__(512, 2) void attn(const ushort* __restrict__ Qg,
                                               const ushort* __restrict__ Kg,
                                               const ushort* __restrict__ Vt,
                                               float* __restrict__ out) {
  __shared__ __align__(16) char smem[8 * 2048 + 1024];  // 8x2KB P | 1KB sml; sO overlays P
  const int tid = threadIdx.x;
  const int lane = tid & 63;
  const int wv = tid >> 6;
  const int cl = lane & 15;
  const int g4 = lane >> 4;
  const int bid = blockIdx.x;
  const int swz = (bid & 7) * 64 + (bid >> 3);  // XCD-chunked (512 % 8 == 0)
  const int b = swz >> 7;
  const int q0 = (swz & 127) << 4;

  char* sPb = smem + wv * 2048;            // [16 q][32 kv] bf16 x2 tiles, swizzled
  float* sml = (float*)(smem + 16384);     // [8][16][2]
  float* sO = (float*)smem;                // merge overlay (after loop)

  // Q B-frag (pre-scaled): lane holds Q[q0+cl][kk*32 + g4*8 ..+7]
  s16x8 qf_[4];
  {
    const ushort* qbase = Qg + (size_t)(b * TSEQ + q0 + cl) * HS;
    for (int kk = 0; kk < 4; ++kk)
      qf_[kk] = *reinterpret_cast<const s16x8*>(qbase + kk * 32 + g4 * 8);
  }

  const ushort* kbase = Kg + (size_t)b * TSEQ * HS;
  const ushort* vbase = Vt + (size_t)b * HS * TSEQ;
  const int pswz = (cl & 3) << 4;

  f32x4 o_[8] = {};                 // O[d=df*16+g4*4+r][q=cl]
  float m_ = -3.0e38f, l_ = 0.f;    // per-lane (q=cl) running stats

  const int kvwave = wv * 256;
  for (int ti = 0; ti < 4; ++ti) {
    const int kvA = kvwave + ti * 64;
    const int kvB = kvA + 32;
    // K A-frags for both tiles, direct from global (32B/lane in flight)
    s16x8 kfA[2][4], kfB[2][4];
    for (int kvf = 0; kvf < 2; ++kvf)
      for (int kk = 0; kk < 4; ++kk) {
        kfA[kvf][kk] = *reinterpret_cast<const s16x8*>(
            kbase + (size_t)(kvA + kvf * 16 + cl) * HS + kk * 32 + g4 * 8);
        kfB[kvf][kk] = *reinterpret_cast<const s16x8*>(
            kbase + (size_t)(kvB + kvf * 16 + cl) * HS + kk * 32 + g4 * 8);
      }

    // Two independent QK^T chains: S[kv=kvf*16+g4*4+r][q=cl]
    f32x4 sA[2] = {}, sB[2] = {};
    for (int kk = 0; kk < 4; ++kk) {
      sA[0] = __builtin_amdgcn_mfma_f32_16x16x32_bf16(kfA[0][kk], qf_[kk], sA[0], 0, 0, 0);
      sA[1] = __builtin_amdgcn_mfma_f32_16x16x32_bf16(kfA[1][kk], qf_[kk], sA[1], 0, 0, 0);
      sB[0] = __builtin_amdgcn_mfma_f32_16x16x32_bf16(kfB[0][kk], qf_[kk], sB[0], 0, 0, 0);
      sB[1] = __builtin_amdgcn_mfma_f32_16x16x32_bf16(kfB[1][kk], qf_[kk], sB[1], 0, 0, 0);
    }

    // V A-frags for both tiles (issue early, consumed after softmax)
    s16x8 vfA[8], vfB[8];
    for (int df = 0; df < 8; ++df) {
      vfA[df] = *reinterpret_cast<const s16x8*>(
          vbase + (size_t)(df * 16 + cl) * TSEQ + kvA + g4 * 8);
      vfB[df] = *reinterpret_cast<const s16x8*>(
          vbase + (size_t)(df * 16 + cl) * TSEQ + kvB + g4 * 8);
    }

    // ONE online-softmax update over all 16 in-lane values
    float mx = sA[0][0];
    for (int r = 1; r < 4; ++r) mx = fmaxf(mx, sA[0][r]);
    for (int r = 0; r < 4; ++r) mx = fmaxf(mx, sA[1][r]);
    for (int r = 0; r < 4; ++r) mx = fmaxf(mx, sB[0][r]);
    for (int r = 0; r < 4; ++r) mx = fmaxf(mx, sB[1][r]);
    mx = fmaxf(mx, __shfl_xor(mx, 16, 64));
    mx = fmaxf(mx, __shfl_xor(mx, 32, 64));
    float mn = fmaxf(m_, mx);
    float al = __expf(m_ - mn);
    m_ = mn;
    float pA0[4], pA1[4], pB0[4], pB1[4], rs = 0.f;
    for (int r = 0; r < 4; ++r) { pA0[r] = __expf(sA[0][r] - mn); rs += pA0[r]; }
    for (int r = 0; r < 4; ++r) { pA1[r] = __expf(sA[1][r] - mn); rs += pA1[r]; }
    for (int r = 0; r < 4; ++r) { pB0[r] = __expf(sB[0][r] - mn); rs += pB0[r]; }
    for (int r = 0; r < 4; ++r) { pB1[r] = __expf(sB[1][r] - mn); rs += pB1[r]; }
    rs += __shfl_xor(rs, 16, 64);
    rs += __shfl_xor(rs, 32, 64);
    l_ = l_ * al + rs;
    for (int df = 0; df < 8; ++df)
      for (int r = 0; r < 4; ++r) o_[df][r] *= al;

    // P -> LDS transpose, both tiles (tile A at +0, tile B at +1024)
    {
      ushort4 wA0, wA1, wB0, wB1;
      wA0.x = f2bf(pA0[0]); wA0.y = f2bf(pA0[1]); wA0.z = f2bf(pA0[2]); wA0.w = f2bf(pA0[3]);
      wA1.x = f2bf(pA1[0]); wA1.y = f2bf(pA1[1]); wA1.z = f2bf(pA1[2]); wA1.w = f2bf(pA1[3]);
      wB0.x = f2bf(pB0[0]); wB0.y = f2bf(pB0[1]); wB0.z = f2bf(pB0[2]); wB0.w = f2bf(pB0[3]);
      wB1.x = f2bf(pB1[0]); wB1.y = f2bf(pB1[1]); wB1.z = f2bf(pB1[2]); wB1.w = f2bf(pB1[3]);
      *reinterpret_cast<ushort4*>(sPb + ((cl * 64 + 0 * 32 + g4 * 8) ^ pswz)) = wA0;
      *reinterpret_cast<ushort4*>(sPb + ((cl * 64 + 1 * 32 + g4 * 8) ^ pswz)) = wA1;
      *reinterpret_cast<ushort4*>(sPb + 1024 + ((cl * 64 + 0 * 32 + g4 * 8) ^ pswz)) = wB0;
      *reinterpret_cast<ushort4*>(sPb + 1024 + ((cl * 64 + 1 * 32 + g4 * 8) ^ pswz)) = wB1;
    }
    s16x8 pafA = *reinterpret_cast<const s16x8*>(sPb + ((cl * 64 + g4 * 16) ^ pswz));
    s16x8 pafB = *reinterpret_cast<const s16x8*>(sPb + 1024 + ((cl * 64 + g4 * 16) ^ pswz));

    // O += V^T·P for both tiles: 16 MFMAs, 2x independent per df
    for (int df = 0; df < 8; ++df) {
      o_[df] = __builtin_amdgcn_mfma_f32_16x16x32_bf16(vfA[df], pafA, o_[df], 0, 0, 0);
      o_[df] = __builtin_amdgcn_mfma_f32_16x16x32_bf16(vfB[df], pafB, o_[df], 0, 0, 0);
    }
  }

  // ---- merge the 8 kv-split partials (per-lane stats, LDS atomics) ----
  if (g4 == 0) {
    sml[(wv * 16 + cl) * 2 + 0] = m_;
    sml[(wv * 16 + cl) * 2 + 1] = l_;
  }
  __syncthreads();
  float M = -3.0e38f;
  for (int w = 0; w < 8; ++w) M = fmaxf(M, sml[(w * 16 + cl) * 2]);
  float L = 0.f;
  for (int w = 0; w < 8; ++w) L += sml[(w * 16 + cl) * 2 + 1] * __expf(sml[(w * 16 + cl) * 2] - M);
  const float fac = __expf(m_ - M) / L;
  __syncthreads();  // sml read done; sO overlays P region
  for (int i = tid; i < 16 * HS; i += 512) sO[i] = 0.f;
  __syncthreads();
  for (int df = 0; df < 8; ++df)
    for (int r = 0; r < 4; ++r)
      atomicAdd(&sO[cl * HS + df * 16 + g4 * 4 + r], o_[df][r] * fac);
  __syncthreads();
  float* op = out + (size_t)(b * TSEQ + q0) * HS;
  reinterpret_cast<float4*>(op)[tid] = reinterpret_cast<const float4*>(sO)[tid];
}

extern "C" void kernel_launch(void* const* d_in, const int* in_sizes, int n_in,
                              void* d_out, int out_size, void* d_ws, size_t ws_size,
                              hipStream_t stream) {
  const float* x = (const float*)d_in[0];
  const float* Wq = (const float*)d_in[1];
  const float* bq = (const float*)d_in[2];
  const float* Wk = (const float*)d_in[3];
  const float* bk = (const float*)d_in[4];
  const float* Wv = (const float*)d_in[5];
  const float* bv = (const float*)d_in[6];
  float* out = (float*)d_out;

  char* ws = (char*)d_ws;
  ushort* xb = (ushort*)ws;                    // 8192*1024 bf16 = 16 MB
  ushort* wc = (ushort*)(ws + 16777216);       // 384*1024 bf16
  ushort* Qb = (ushort*)(ws + 17563648);       // 8192*128 bf16 (pre-scaled)
  ushort* Kb = (ushort*)(ws + 19660800);       // 8192*128 bf16
  ushort* Vt = (ushort*)(ws + 21757952);       // 4*128*2048 bf16 (transposed V)

  cvt4<<<8192, 256, 0, stream>>>(x, xb, 2097152);
  cvtW<<<384, 256, 0, stream>>>(Wq, Wk, Wv, wc);
  qkv_gemm<<<dim3(128, 3), 256, 0, stream>>>(xb, wc, bq, bk, bv, Qb, Kb, Vt);
  attn<<<512, 512, 0, stream>>>(Qb, Kb, Vt, out);
}